// Round 5
// baseline (208.632 us; speedup 1.0000x reference)
//
#include <hip/hip_runtime.h>
#include <math.h>

#define NN 1024    // 32*32 tokens per batch

typedef __attribute__((ext_vector_type(8))) __bf16 bf16x8;
typedef __attribute__((ext_vector_type(4))) __bf16 bf16x4;
typedef __attribute__((ext_vector_type(4))) float f32x4;

// Native f32->bf16 (gfx950 v_cvt_pk_bf16_f32 via fptrunc; RNE)
__device__ __forceinline__ unsigned short f2bf(float f) {
    __bf16 h = (__bf16)f;
    return *(unsigned short*)&h;
}
__device__ __forceinline__ ushort4 pack4(float a, float b, float c, float d) {
    bf16x4 v;
    v[0] = (__bf16)a; v[1] = (__bf16)b; v[2] = (__bf16)c; v[3] = (__bf16)d;
    return *(ushort4*)&v;
}

// ---------------- Kernel 0: transpose + bf16 prep --------------------------
// x [16][256][1024] f32 -> xb [16*1024][256] bf16        (256 col-tiles x16 b)
// W_qkv [256][768] f32  -> Wqt [768][256] bf16           (12 col-tiles)
// W_out [256][256] f32  -> Wot [256][256] bf16 (transp)  (4 col-tiles)
__global__ __launch_bounds__(256) void prep_transpose(
    const float* __restrict__ x, const float* __restrict__ Wq,
    const float* __restrict__ Wo,
    unsigned short* __restrict__ xb, unsigned short* __restrict__ Wqt,
    unsigned short* __restrict__ Wot)
{
    __shared__ __align__(16) unsigned short T[64 * 72];  // [r][c] bf16, pad 72
    const int bx = blockIdx.x;   // 0..271
    const int rt = blockIdx.y;   // row tile (of 256 rows) 0..3
    const float* src; unsigned short* dst; int ncol, c0;
    if (bx < 256) {
        int b = bx >> 4; int ct = bx & 15;
        src = x + (size_t)b * 256 * 1024; dst = xb + (size_t)b * 1024 * 256;
        ncol = 1024; c0 = ct * 64;
    } else if (bx < 268) {
        src = Wq; dst = Wqt; ncol = 768; c0 = (bx - 256) * 64;
    } else {
        src = Wo; dst = Wot; ncol = 256; c0 = (bx - 268) * 64;
    }
    const int t = threadIdx.x;
    #pragma unroll
    for (int i = 0; i < 4; ++i) {
        int r  = i * 16 + (t >> 4);
        int c4 = (t & 15) * 4;
        float4 v = *(const float4*)&src[(size_t)(rt * 64 + r) * ncol + c0 + c4];
        *(ushort4*)&T[r * 72 + c4] = pack4(v.x, v.y, v.z, v.w);
    }
    __syncthreads();
    // column gather (2-way bank aliasing only) -> coalesced store
    #pragma unroll
    for (int i = 0; i < 2; ++i) {
        int task = t + 256 * i;          // 0..511
        int c = task & 63, rs = task >> 6;
        ushort u8[8];
        #pragma unroll
        for (int k = 0; k < 8; ++k) u8[k] = T[(rs * 8 + k) * 72 + c];
        *(uint4*)&dst[(size_t)(c0 + c) * 256 + rt * 64 + rs * 8] = *(uint4*)u8;
    }
}

// ---------------- Kernel 1: bf16 MFMA QKV GEMM (pipelined) -----------------
// D[m][j] = xb[m][:] . Wqt[j][:]  (m = b*1024+n, j in 0..767)
// 128x128 tile, BK=32, 4 waves (2m x 2j), wave = 64x64 via 4x4 16x16x32 MFMAs.
// Epilogue: Qb/Kb [bh][n][64] (Q pre-scaled 0.125), Vtb [bh][64][n].
__global__ __launch_bounds__(256, 4) void qkv_gemm(
    const unsigned short* __restrict__ xb, const unsigned short* __restrict__ Wqt,
    const float* __restrict__ bias,
    unsigned short* __restrict__ Qb, unsigned short* __restrict__ Kb,
    unsigned short* __restrict__ Vtb)
{
    __shared__ __align__(16) unsigned short As[128 * 40];  // [m][k] stride 40
    __shared__ __align__(16) unsigned short Bs[128 * 40];  // [j][k]
    const int jt = blockIdx.x;        // 0..5
    const int m0 = blockIdx.y * 128;
    const int b  = m0 >> 10;
    const int n0 = m0 & 1023;
    const int t = threadIdx.x;
    const int w = t >> 6, lane = t & 63, quad = lane >> 4, cc = lane & 15;
    const int wm = (w & 1) * 64;
    const int wj = (w >> 1) * 64;

    f32x4 acc[4][4];
    #pragma unroll
    for (int ms = 0; ms < 4; ++ms)
        #pragma unroll
        for (int js = 0; js < 4; ++js) acc[ms][js] = (f32x4)(0.f);

    // prefetch k-slab 0
    uint4 areg[2], breg[2];
    #pragma unroll
    for (int i = 0; i < 2; ++i) {
        int flat = t + 256 * i;
        int row = flat >> 2, seg = flat & 3;
        areg[i] = *(const uint4*)&xb[(size_t)(m0 + row) * 256 + seg * 8];
        breg[i] = *(const uint4*)&Wqt[(size_t)(jt * 128 + row) * 256 + seg * 8];
    }

    for (int kk = 0; kk < 8; ++kk) {
        __syncthreads();   // prev compute done; drains prefetch loads
        #pragma unroll
        for (int i = 0; i < 2; ++i) {
            int flat = t + 256 * i;
            int row = flat >> 2, seg = flat & 3;
            *(uint4*)&As[row * 40 + seg * 8] = areg[i];
            *(uint4*)&Bs[row * 40 + seg * 8] = breg[i];
        }
        __syncthreads();
        // prefetch next slab AFTER the barrier -> flies during compute
        int kn = ((kk + 1) & 7) * 32;
        #pragma unroll
        for (int i = 0; i < 2; ++i) {
            int flat = t + 256 * i;
            int row = flat >> 2, seg = flat & 3;
            areg[i] = *(const uint4*)&xb[(size_t)(m0 + row) * 256 + kn + seg * 8];
            breg[i] = *(const uint4*)&Wqt[(size_t)(jt * 128 + row) * 256 + kn + seg * 8];
        }
        bf16x8 af[4], bfr[4];
        #pragma unroll
        for (int ms = 0; ms < 4; ++ms)
            af[ms] = *(bf16x8*)&As[(wm + ms * 16 + cc) * 40 + quad * 8];
        #pragma unroll
        for (int js = 0; js < 4; ++js)
            bfr[js] = *(bf16x8*)&Bs[(wj + js * 16 + cc) * 40 + quad * 8];
        #pragma unroll
        for (int ms = 0; ms < 4; ++ms)
            #pragma unroll
            for (int js = 0; js < 4; ++js)
                acc[ms][js] = __builtin_amdgcn_mfma_f32_16x16x32_bf16(
                    af[ms], bfr[js], acc[ms][js], 0, 0, 0);
    }

    // wave's 64 j-columns = one uniform 64-chunk: chunk = jt*2 + (w>>1)
    const int chunk = jt * 2 + (w >> 1);
    const int h = chunk / 3, type = chunk % 3;   // 0=q 1=k 2=v
    const size_t bh = (size_t)b * 4 + h;
    float bias_r[4];
    #pragma unroll
    for (int js = 0; js < 4; ++js) bias_r[js] = bias[jt * 128 + wj + js * 16 + cc];

    if (type == 2) {
        // Vtb[bh][d][n]: lane owns row d = js*16+cc, ushort4 along n (regs)
        #pragma unroll
        for (int ms = 0; ms < 4; ++ms)
            #pragma unroll
            for (int js = 0; js < 4; ++js) {
                int dd = js * 16 + cc;
                int n = n0 + wm + ms * 16 + quad * 4;
                *(ushort4*)&Vtb[(bh * 64 + dd) * NN + n] =
                    pack4(acc[ms][js][0] + bias_r[js], acc[ms][js][1] + bias_r[js],
                          acc[ms][js][2] + bias_r[js], acc[ms][js][3] + bias_r[js]);
            }
    } else {
        unsigned short* dst = type ? Kb : Qb;
        const float sc = type ? 1.0f : 0.125f;   // 64^-0.5 folded into Q
        #pragma unroll
        for (int ms = 0; ms < 4; ++ms)
            #pragma unroll
            for (int js = 0; js < 4; ++js)
                #pragma unroll
                for (int r = 0; r < 4; ++r) {
                    int n = n0 + wm + ms * 16 + quad * 4 + r;
                    dst[(bh * NN + n) * 64 + js * 16 + cc] =
                        f2bf((acc[ms][js][r] + bias_r[js]) * sc);
                }
    }
}

// ---------------- Kernel 2: bf16-MFMA flash attention (pipelined) ----------
__global__ __launch_bounds__(256, 4) void flash_attn(
    const unsigned short* __restrict__ Qb, const unsigned short* __restrict__ Kb,
    const unsigned short* __restrict__ Vtb, unsigned short* __restrict__ resb)
{
    __shared__ __align__(16) unsigned short Qs[64 * 72];
    __shared__ __align__(16) unsigned short Ks[64 * 72];
    __shared__ __align__(16) unsigned short Vt[64 * 72];
    __shared__ __align__(16) unsigned short Ps[64 * 72];

    const int blk = blockIdx.x;
    const int qt = blk & 15;
    const int h  = (blk >> 4) & 3;
    const int b  = blk >> 6;
    const int t  = threadIdx.x;
    const int w  = t >> 6;
    const int lane = t & 63;
    const int quad = lane >> 4;
    const int c    = lane & 15;

    const size_t bh = (size_t)(b * 4 + h);
    const unsigned short* Qg = Qb  + bh * NN * 64;
    const unsigned short* Kg = Kb  + bh * NN * 64;
    const unsigned short* Vg = Vtb + bh * 64 * NN;

    // stage Q tile + prefetch K/V tile 0 into registers
    uint4 kreg[2], vreg[2];
    #pragma unroll
    for (int i = 0; i < 2; ++i) {
        int flat = t + 256 * i;
        int row = flat >> 3, seg = flat & 7;
        *(uint4*)&Qs[row * 72 + seg * 8] =
            *(const uint4*)&Qg[(size_t)(qt * 64 + row) * 64 + seg * 8];
        kreg[i] = *(const uint4*)&Kg[(size_t)row * 64 + seg * 8];
        vreg[i] = *(const uint4*)&Vg[(size_t)row * NN + seg * 8];
    }
    __syncthreads();
    // Q fragments are loop-invariant: hoist
    bf16x8 qf[2];
    qf[0] = *(bf16x8*)&Qs[(w * 16 + c) * 72 + 0 * 32 + quad * 8];
    qf[1] = *(bf16x8*)&Qs[(w * 16 + c) * 72 + 1 * 32 + quad * 8];

    float m_i = -INFINITY, l_i = 0.f;
    f32x4 O[4];
    #pragma unroll
    for (int dt = 0; dt < 4; ++dt) O[dt] = (f32x4)(0.f);

    for (int kt = 0; kt < 16; ++kt) {
        __syncthreads();   // prev compute done reading LDS; drains prefetch loads
        #pragma unroll
        for (int i = 0; i < 2; ++i) {
            int flat = t + 256 * i;
            int row = flat >> 3, seg = flat & 7;
            *(uint4*)&Ks[row * 72 + seg * 8] = kreg[i];
            *(uint4*)&Vt[row * 72 + seg * 8] = vreg[i];
        }
        __syncthreads();
        // prefetch next K/V tile AFTER barrier -> overlaps with compute below
        int ktn = (kt + 1) & 15;
        #pragma unroll
        for (int i = 0; i < 2; ++i) {
            int flat = t + 256 * i;
            int row = flat >> 3, seg = flat & 7;
            kreg[i] = *(const uint4*)&Kg[(size_t)(ktn * 64 + row) * 64 + seg * 8];
            vreg[i] = *(const uint4*)&Vg[(size_t)row * NN + ktn * 64 + seg * 8];
        }

        f32x4 S[4];
        #pragma unroll
        for (int jt = 0; jt < 4; ++jt) S[jt] = (f32x4)(0.f);
        #pragma unroll
        for (int ks = 0; ks < 2; ++ks) {
            #pragma unroll
            for (int jt = 0; jt < 4; ++jt) {
                bf16x8 kf = *(bf16x8*)&Ks[(jt * 16 + c) * 72 + ks * 32 + quad * 8];
                S[jt] = __builtin_amdgcn_mfma_f32_16x16x32_bf16(kf, qf[ks], S[jt], 0, 0, 0);
            }
        }

        float mt = -INFINITY;
        #pragma unroll
        for (int jt = 0; jt < 4; ++jt)
            #pragma unroll
            for (int r = 0; r < 4; ++r) mt = fmaxf(mt, S[jt][r]);
        mt = fmaxf(mt, __shfl_xor(mt, 16));
        mt = fmaxf(mt, __shfl_xor(mt, 32));
        float mn = fmaxf(m_i, mt);
        float alpha = __expf(m_i - mn);
        float p[4][4];
        float rs = 0.f;
        #pragma unroll
        for (int jt = 0; jt < 4; ++jt)
            #pragma unroll
            for (int r = 0; r < 4; ++r) {
                p[jt][r] = __expf(S[jt][r] - mn);
                rs += p[jt][r];
            }
        rs += __shfl_xor(rs, 16);
        rs += __shfl_xor(rs, 32);
        l_i = l_i * alpha + rs;
        m_i = mn;

        #pragma unroll
        for (int jt = 0; jt < 4; ++jt)
            *(ushort4*)&Ps[(w * 16 + c) * 72 + jt * 16 + quad * 4] =
                pack4(p[jt][0], p[jt][1], p[jt][2], p[jt][3]);

        float alpha_r[4];
        #pragma unroll
        for (int r = 0; r < 4; ++r) alpha_r[r] = __shfl(alpha, quad * 4 + r);
        #pragma unroll
        for (int dt = 0; dt < 4; ++dt)
            #pragma unroll
            for (int r = 0; r < 4; ++r) O[dt][r] *= alpha_r[r];

        #pragma unroll
        for (int js = 0; js < 2; ++js) {
            bf16x8 pf = *(bf16x8*)&Ps[(w * 16 + c) * 72 + js * 32 + quad * 8];
            #pragma unroll
            for (int dt = 0; dt < 4; ++dt) {
                bf16x8 vf = *(bf16x8*)&Vt[(dt * 16 + c) * 72 + js * 32 + quad * 8];
                O[dt] = __builtin_amdgcn_mfma_f32_16x16x32_bf16(pf, vf, O[dt], 0, 0, 0);
            }
        }
    }

    float linv[4];
    #pragma unroll
    for (int r = 0; r < 4; ++r) linv[r] = 1.f / __shfl(l_i, quad * 4 + r);
    #pragma unroll
    for (int dt = 0; dt < 4; ++dt)
        #pragma unroll
        for (int r = 0; r < 4; ++r) {
            int row = qt * 64 + w * 16 + quad * 4 + r;
            resb[((size_t)(b * NN + row)) * 256 + h * 64 + dt * 16 + c] =
                f2bf(O[dt][r] * linv[r]);
        }
}

// ---------------- Kernel 3: bf16 MFMA out GEMM + bias + residual -----------
// out[b][c][n] = res[b*1024+n][:] . Wot[c][:] + b_out[c] + x[b][c][n]
// 64x64 tile, 4 waves (2m x 2j), wave = 32x32 via 2x2 MFMAs. f32 output.
__global__ __launch_bounds__(256, 4) void out_gemm(
    const unsigned short* __restrict__ resb, const unsigned short* __restrict__ Wot,
    const float* __restrict__ bias, const float* __restrict__ x,
    float* __restrict__ out)
{
    __shared__ __align__(16) unsigned short As[64 * 40];  // res [m][k]
    __shared__ __align__(16) unsigned short Bs[64 * 40];  // Wot [j][k]
    const int n0 = blockIdx.x * 64;
    const int c0 = blockIdx.y * 64;
    const int b  = blockIdx.z;
    const int t = threadIdx.x;
    const int w = t >> 6, lane = t & 63, quad = lane >> 4, cc = lane & 15;
    const int wm = (w & 1) * 32;
    const int wj = (w >> 1) * 32;
    const int r = t >> 2, seg = t & 3;    // 64 rows x 32 k per buffer

    f32x4 acc[2][2];
    #pragma unroll
    for (int ms = 0; ms < 2; ++ms)
        #pragma unroll
        for (int js = 0; js < 2; ++js) acc[ms][js] = (f32x4)(0.f);

    uint4 areg = *(const uint4*)&resb[((size_t)b * NN + n0 + r) * 256 + seg * 8];
    uint4 breg = *(const uint4*)&Wot[(size_t)(c0 + r) * 256 + seg * 8];

    for (int kk = 0; kk < 8; ++kk) {
        __syncthreads();
        *(uint4*)&As[r * 40 + seg * 8] = areg;
        *(uint4*)&Bs[r * 40 + seg * 8] = breg;
        __syncthreads();
        int kn = ((kk + 1) & 7) * 32;
        areg = *(const uint4*)&resb[((size_t)b * NN + n0 + r) * 256 + kn + seg * 8];
        breg = *(const uint4*)&Wot[(size_t)(c0 + r) * 256 + kn + seg * 8];
        bf16x8 af[2], bfr[2];
        #pragma unroll
        for (int ms = 0; ms < 2; ++ms)
            af[ms] = *(bf16x8*)&As[(wm + ms * 16 + cc) * 40 + quad * 8];
        #pragma unroll
        for (int js = 0; js < 2; ++js)
            bfr[js] = *(bf16x8*)&Bs[(wj + js * 16 + cc) * 40 + quad * 8];
        #pragma unroll
        for (int ms = 0; ms < 2; ++ms)
            #pragma unroll
            for (int js = 0; js < 2; ++js)
                acc[ms][js] = __builtin_amdgcn_mfma_f32_16x16x32_bf16(
                    af[ms], bfr[js], acc[ms][js], 0, 0, 0);
    }

    #pragma unroll
    for (int js = 0; js < 2; ++js) {
        int cI = c0 + wj + js * 16 + cc;
        float bi = bias[cI];
        #pragma unroll
        for (int ms = 0; ms < 2; ++ms) {
            int n = n0 + wm + ms * 16 + quad * 4;
            size_t off = ((size_t)b * 256 + cI) * NN + n;
            float4 xr = *(const float4*)&x[off];
            float4 o;
            o.x = acc[ms][js][0] + bi + xr.x;
            o.y = acc[ms][js][1] + bi + xr.y;
            o.z = acc[ms][js][2] + bi + xr.z;
            o.w = acc[ms][js][3] + bi + xr.w;
            *(float4*)&out[off] = o;
        }
    }
}

extern "C" void kernel_launch(void* const* d_in, const int* in_sizes, int n_in,
                              void* d_out, int out_size, void* d_ws, size_t ws_size,
                              hipStream_t stream)
{
    const float* x     = (const float*)d_in[0];
    const float* W_qkv = (const float*)d_in[1];
    const float* b_qkv = (const float*)d_in[2];
    const float* W_out = (const float*)d_in[3];
    const float* b_out = (const float*)d_in[4];
    float* out = (float*)d_out;

    // ws: xb 8MB | Wqt 384KB | Wot 128KB | Qb 8MB | Kb 8MB | Vtb 8MB | resb 8MB
    char* wsc = (char*)d_ws;
    unsigned short* xb   = (unsigned short*)(wsc);
    unsigned short* Wqt  = (unsigned short*)(wsc + ((size_t)8 << 20));
    unsigned short* Wot  = (unsigned short*)(wsc + ((size_t)8 << 20) + ((size_t)512 << 10));
    unsigned short* Qb   = (unsigned short*)(wsc + ((size_t)9  << 20));
    unsigned short* Kb   = (unsigned short*)(wsc + ((size_t)17 << 20));
    unsigned short* Vtb  = (unsigned short*)(wsc + ((size_t)25 << 20));
    unsigned short* resb = (unsigned short*)(wsc + ((size_t)33 << 20));

    prep_transpose<<<dim3(272, 4), 256, 0, stream>>>(x, W_qkv, W_out, xb, Wqt, Wot);
    qkv_gemm<<<dim3(6, 128), 256, 0, stream>>>(xb, Wqt, b_qkv, Qb, Kb, Vtb);
    flash_attn<<<dim3(1024), 256, 0, stream>>>(Qb, Kb, Vtb, resb);
    out_gemm<<<dim3(16, 4, 16), 256, 0, stream>>>(resb, Wot, b_out, x, out);
}

// Round 6
// 146.936 us; speedup vs baseline: 1.4199x; 1.4199x over previous
//
#include <hip/hip_runtime.h>
#include <math.h>

#define NN 1024    // 32*32 tokens per batch

typedef __attribute__((ext_vector_type(8))) __bf16 bf16x8;
typedef __attribute__((ext_vector_type(4))) __bf16 bf16x4;
typedef __attribute__((ext_vector_type(4))) float f32x4;

// Native f32->bf16 (RNE via fptrunc)
__device__ __forceinline__ unsigned short f2bf(float f) {
    __bf16 h = (__bf16)f;
    return *(unsigned short*)&h;
}
__device__ __forceinline__ ushort4 pack4(float a, float b, float c, float d) {
    bf16x4 v;
    v[0] = (__bf16)a; v[1] = (__bf16)b; v[2] = (__bf16)c; v[3] = (__bf16)d;
    return *(ushort4*)&v;
}

// Async global->LDS, 16B per lane. LDS dest must be wave-linear: base + lane*16.
__device__ __forceinline__ void async_cp16(const unsigned short* g, unsigned short* l) {
    __builtin_amdgcn_global_load_lds(
        (const __attribute__((address_space(1))) unsigned int*)g,
        (__attribute__((address_space(3))) unsigned int*)l,
        16, 0, 0);
}

// ---------------- Kernel 0: transpose + bf16 prep --------------------------
__global__ __launch_bounds__(256) void prep_transpose(
    const float* __restrict__ x, const float* __restrict__ Wq,
    const float* __restrict__ Wo,
    unsigned short* __restrict__ xb, unsigned short* __restrict__ Wqt,
    unsigned short* __restrict__ Wot)
{
    __shared__ __align__(16) unsigned short T[64 * 72];  // [r][c] bf16, pad 72
    const int bx = blockIdx.x;   // 0..271
    const int rt = blockIdx.y;   // row tile (of 256 rows) 0..3
    const float* src; unsigned short* dst; int ncol, c0;
    if (bx < 256) {
        int b = bx >> 4; int ct = bx & 15;
        src = x + (size_t)b * 256 * 1024; dst = xb + (size_t)b * 1024 * 256;
        ncol = 1024; c0 = ct * 64;
    } else if (bx < 268) {
        src = Wq; dst = Wqt; ncol = 768; c0 = (bx - 256) * 64;
    } else {
        src = Wo; dst = Wot; ncol = 256; c0 = (bx - 268) * 64;
    }
    const int t = threadIdx.x;
    #pragma unroll
    for (int i = 0; i < 4; ++i) {
        int r  = i * 16 + (t >> 4);
        int c4 = (t & 15) * 4;
        float4 v = *(const float4*)&src[(size_t)(rt * 64 + r) * ncol + c0 + c4];
        *(ushort4*)&T[r * 72 + c4] = pack4(v.x, v.y, v.z, v.w);
    }
    __syncthreads();
    #pragma unroll
    for (int i = 0; i < 2; ++i) {
        int task = t + 256 * i;          // 0..511
        int c = task & 63, rs = task >> 6;
        ushort u8[8];
        #pragma unroll
        for (int k = 0; k < 8; ++k) u8[k] = T[(rs * 8 + k) * 72 + c];
        *(uint4*)&dst[(size_t)(c0 + c) * 256 + rt * 64 + rs * 8] = *(uint4*)u8;
    }
}

// ---------------- Kernel 1: bf16 MFMA QKV GEMM (R4-proven structure) -------
__global__ __launch_bounds__(256, 4) void qkv_gemm(
    const unsigned short* __restrict__ xb, const unsigned short* __restrict__ Wqt,
    const float* __restrict__ bias,
    unsigned short* __restrict__ Qb, unsigned short* __restrict__ Kb,
    unsigned short* __restrict__ Vtb)
{
    __shared__ __align__(16) unsigned short As[128 * 40];  // [m][k] stride 40
    __shared__ __align__(16) unsigned short Bs[128 * 40];  // [j][k]
    const int jt = blockIdx.x;        // 0..5
    const int m0 = blockIdx.y * 128;
    const int b  = m0 >> 10;
    const int n0 = m0 & 1023;
    const int t = threadIdx.x;
    const int w = t >> 6, lane = t & 63, quad = lane >> 4, cc = lane & 15;
    const int wm = (w & 1) * 64;
    const int wj = (w >> 1) * 64;

    f32x4 acc[4][4];
    #pragma unroll
    for (int ms = 0; ms < 4; ++ms)
        #pragma unroll
        for (int js = 0; js < 4; ++js) acc[ms][js] = (f32x4)(0.f);

    for (int k0 = 0; k0 < 256; k0 += 32) {
        __syncthreads();
        #pragma unroll
        for (int i = 0; i < 2; ++i) {
            int flat = t + 256 * i;
            int row = flat >> 2, seg = flat & 3;
            *(uint4*)&As[row * 40 + seg * 8] =
                *(const uint4*)&xb[(size_t)(m0 + row) * 256 + k0 + seg * 8];
            *(uint4*)&Bs[row * 40 + seg * 8] =
                *(const uint4*)&Wqt[(size_t)(jt * 128 + row) * 256 + k0 + seg * 8];
        }
        __syncthreads();
        bf16x8 af[4], bfr[4];
        #pragma unroll
        for (int ms = 0; ms < 4; ++ms)
            af[ms] = *(bf16x8*)&As[(wm + ms * 16 + cc) * 40 + quad * 8];
        #pragma unroll
        for (int js = 0; js < 4; ++js)
            bfr[js] = *(bf16x8*)&Bs[(wj + js * 16 + cc) * 40 + quad * 8];
        #pragma unroll
        for (int ms = 0; ms < 4; ++ms)
            #pragma unroll
            for (int js = 0; js < 4; ++js)
                acc[ms][js] = __builtin_amdgcn_mfma_f32_16x16x32_bf16(
                    af[ms], bfr[js], acc[ms][js], 0, 0, 0);
    }

    const int chunk = jt * 2 + (w >> 1);
    const int h = chunk / 3, type = chunk % 3;   // 0=q 1=k 2=v
    const size_t bh = (size_t)b * 4 + h;
    float bias_r[4];
    #pragma unroll
    for (int js = 0; js < 4; ++js) bias_r[js] = bias[jt * 128 + wj + js * 16 + cc];

    if (type == 2) {
        #pragma unroll
        for (int ms = 0; ms < 4; ++ms)
            #pragma unroll
            for (int js = 0; js < 4; ++js) {
                int dd = js * 16 + cc;
                int n = n0 + wm + ms * 16 + quad * 4;
                *(ushort4*)&Vtb[(bh * 64 + dd) * NN + n] =
                    pack4(acc[ms][js][0] + bias_r[js], acc[ms][js][1] + bias_r[js],
                          acc[ms][js][2] + bias_r[js], acc[ms][js][3] + bias_r[js]);
            }
    } else {
        unsigned short* dst = type ? Kb : Qb;
        const float sc = type ? 1.0f : 0.125f;   // 64^-0.5 folded into Q
        #pragma unroll
        for (int ms = 0; ms < 4; ++ms)
            #pragma unroll
            for (int js = 0; js < 4; ++js)
                #pragma unroll
                for (int r = 0; r < 4; ++r) {
                    int n = n0 + wm + ms * 16 + quad * 4 + r;
                    dst[(bh * NN + n) * 64 + js * 16 + cc] =
                        f2bf((acc[ms][js][r] + bias_r[js]) * sc);
                }
    }
}

// ---------------- Kernel 2: flash attention, async-DMA double-buffered -----
// Unpadded LDS tiles (stride 64 shorts) + XOR chunk swizzle on the global
// address side: storage chunk sc of row r holds global 16B-chunk sc^(r&7).
// Fragment ds_read_b128 bank groups: (gc ^ (c&7)) -> 2-way, free.
__global__ __launch_bounds__(256) void flash_attn(
    const unsigned short* __restrict__ Qb, const unsigned short* __restrict__ Kb,
    const unsigned short* __restrict__ Vtb, unsigned short* __restrict__ resb)
{
    __shared__ __align__(16) unsigned short Qs[4096];
    __shared__ __align__(16) unsigned short Ks0[4096];
    __shared__ __align__(16) unsigned short Ks1[4096];
    __shared__ __align__(16) unsigned short Vt0[4096];
    __shared__ __align__(16) unsigned short Vt1[4096];
    __shared__ __align__(16) unsigned short Ps[64 * 72];

    const int blk = blockIdx.x;
    const int qt = blk & 15;
    const int h  = (blk >> 4) & 3;
    const int b  = blk >> 6;
    const int t  = threadIdx.x;
    const int w  = t >> 6;
    const int lane = t & 63;
    const int quad = lane >> 4;
    const int c    = lane & 15;

    const size_t bh = (size_t)(b * 4 + h);
    const unsigned short* Qg = Qb  + bh * NN * 64;
    const unsigned short* Kg = Kb  + bh * NN * 64;
    const unsigned short* Vg = Vtb + bh * 64 * NN;

    // Async-stage Q (swizzled) + K/V tile 0 into buf 0
    #pragma unroll
    for (int i = 0; i < 2; ++i) {
        int f = i * 256 + t;             // lane-linear within each wave
        int row = f >> 3;
        int gc  = (f & 7) ^ (row & 7);
        async_cp16(&Qg[(size_t)(qt * 64 + row) * 64 + gc * 8], &Qs[f * 8]);
        async_cp16(&Kg[(size_t)row * 64 + gc * 8], &Ks0[f * 8]);
        async_cp16(&Vg[(size_t)row * NN + gc * 8], &Vt0[f * 8]);
    }
    __syncthreads();   // vmcnt(0) drain + barrier: tile 0 + Q ready

    // Q fragments are loop-invariant: hoist (row = w*16+c, chunk = ks*4+quad)
    bf16x8 qf[2];
    #pragma unroll
    for (int ks = 0; ks < 2; ++ks) {
        int sc_ = (ks * 4 + quad) ^ (c & 7);
        qf[ks] = *(bf16x8*)&Qs[((w * 16 + c) * 8 + sc_) * 8];
    }

    float m_i = -INFINITY, l_i = 0.f;
    f32x4 O[4];
    #pragma unroll
    for (int dt = 0; dt < 4; ++dt) O[dt] = (f32x4)(0.f);

    auto step = [&](int kt, const unsigned short* curK, const unsigned short* curV,
                    unsigned short* nxtK, unsigned short* nxtV,
                    bool pref, bool bar) {
        if (bar) __syncthreads();   // drains this wave's DMA for tile kt; all
                                    // waves done reading the nxt buffers
        if (pref) {
            int ktn = kt + 1;
            #pragma unroll
            for (int i = 0; i < 2; ++i) {
                int f = i * 256 + t;
                int row = f >> 3;
                int gc  = (f & 7) ^ (row & 7);
                async_cp16(&Kg[(size_t)(ktn * 64 + row) * 64 + gc * 8], &nxtK[f * 8]);
                async_cp16(&Vg[(size_t)row * NN + ktn * 64 + gc * 8], &nxtV[f * 8]);
            }
        }

        // S^T = K·Q^T (rows j, cols = this wave's q-rows)
        f32x4 S[4];
        #pragma unroll
        for (int jt = 0; jt < 4; ++jt) S[jt] = (f32x4)(0.f);
        #pragma unroll
        for (int ks = 0; ks < 2; ++ks) {
            #pragma unroll
            for (int jt = 0; jt < 4; ++jt) {
                int sc_ = (ks * 4 + quad) ^ (c & 7);
                bf16x8 kf = *(bf16x8*)&curK[((jt * 16 + c) * 8 + sc_) * 8];
                S[jt] = __builtin_amdgcn_mfma_f32_16x16x32_bf16(kf, qf[ks], S[jt], 0, 0, 0);
            }
        }

        // Online softmax over j (16 vals/lane + cross-quad reduce)
        float mt = -INFINITY;
        #pragma unroll
        for (int jt = 0; jt < 4; ++jt)
            #pragma unroll
            for (int r = 0; r < 4; ++r) mt = fmaxf(mt, S[jt][r]);
        mt = fmaxf(mt, __shfl_xor(mt, 16));
        mt = fmaxf(mt, __shfl_xor(mt, 32));
        float mn = fmaxf(m_i, mt);
        float alpha = __expf(m_i - mn);
        float p[4][4];
        float rs = 0.f;
        #pragma unroll
        for (int jt = 0; jt < 4; ++jt)
            #pragma unroll
            for (int r = 0; r < 4; ++r) {
                p[jt][r] = __expf(S[jt][r] - mn);
                rs += p[jt][r];
            }
        rs += __shfl_xor(rs, 16);
        rs += __shfl_xor(rs, 32);
        l_i = l_i * alpha + rs;
        m_i = mn;

        // P -> LDS (own wave's rows; no barrier needed)
        #pragma unroll
        for (int jt = 0; jt < 4; ++jt)
            *(ushort4*)&Ps[(w * 16 + c) * 72 + jt * 16 + quad * 4] =
                pack4(p[jt][0], p[jt][1], p[jt][2], p[jt][3]);

        float alpha_r[4];
        #pragma unroll
        for (int r = 0; r < 4; ++r) alpha_r[r] = __shfl(alpha, quad * 4 + r);
        #pragma unroll
        for (int dt = 0; dt < 4; ++dt)
            #pragma unroll
            for (int r = 0; r < 4; ++r) O[dt][r] *= alpha_r[r];

        // O += P·V
        #pragma unroll
        for (int js = 0; js < 2; ++js) {
            bf16x8 pf = *(bf16x8*)&Ps[(w * 16 + c) * 72 + js * 32 + quad * 8];
            #pragma unroll
            for (int dt = 0; dt < 4; ++dt) {
                int sc_ = (js * 4 + quad) ^ (c & 7);
                bf16x8 vf = *(bf16x8*)&curV[((dt * 16 + c) * 8 + sc_) * 8];
                O[dt] = __builtin_amdgcn_mfma_f32_16x16x32_bf16(pf, vf, O[dt], 0, 0, 0);
            }
        }
    };

    step(0, Ks0, Vt0, Ks1, Vt1, true, false);
    for (int kt2 = 0; kt2 < 7; ++kt2) {
        int kt = 2 * kt2 + 1;
        step(kt,     Ks1, Vt1, Ks0, Vt0, true, true);
        step(kt + 1, Ks0, Vt0, Ks1, Vt1, true, true);
    }
    step(15, Ks1, Vt1, Ks0, Vt0, false, true);

    float linv[4];
    #pragma unroll
    for (int r = 0; r < 4; ++r) linv[r] = 1.f / __shfl(l_i, quad * 4 + r);
    #pragma unroll
    for (int dt = 0; dt < 4; ++dt)
        #pragma unroll
        for (int r = 0; r < 4; ++r) {
            int row = qt * 64 + w * 16 + quad * 4 + r;
            resb[((size_t)(b * NN + row)) * 256 + h * 64 + dt * 16 + c] =
                f2bf(O[dt][r] * linv[r]);
        }
}

// ---------------- Kernel 3: bf16 MFMA out GEMM (R4-proven structure) -------
__global__ __launch_bounds__(256, 4) void out_gemm(
    const unsigned short* __restrict__ resb, const unsigned short* __restrict__ Wot,
    const float* __restrict__ bias, const float* __restrict__ x,
    float* __restrict__ out)
{
    __shared__ __align__(16) unsigned short As[64 * 40];  // res [m][k]
    __shared__ __align__(16) unsigned short Bs[64 * 40];  // Wot [j][k]
    const int n0 = blockIdx.x * 64;
    const int c0 = blockIdx.y * 64;
    const int b  = blockIdx.z;
    const int t = threadIdx.x;
    const int w = t >> 6, lane = t & 63, quad = lane >> 4, cc = lane & 15;
    const int wm = (w & 1) * 32;
    const int wj = (w >> 1) * 32;

    f32x4 acc[2][2];
    #pragma unroll
    for (int ms = 0; ms < 2; ++ms)
        #pragma unroll
        for (int js = 0; js < 2; ++js) acc[ms][js] = (f32x4)(0.f);

    for (int k0 = 0; k0 < 256; k0 += 32) {
        __syncthreads();
        {
            int r = t >> 2, seg = t & 3;   // 64 rows x 32 k per buffer
            *(uint4*)&As[r * 40 + seg * 8] =
                *(const uint4*)&resb[((size_t)b * NN + n0 + r) * 256 + k0 + seg * 8];
            *(uint4*)&Bs[r * 40 + seg * 8] =
                *(const uint4*)&Wot[(size_t)(c0 + r) * 256 + k0 + seg * 8];
        }
        __syncthreads();
        bf16x8 af[2], bfr[2];
        #pragma unroll
        for (int ms = 0; ms < 2; ++ms)
            af[ms] = *(bf16x8*)&As[(wm + ms * 16 + cc) * 40 + quad * 8];
        #pragma unroll
        for (int js = 0; js < 2; ++js)
            bfr[js] = *(bf16x8*)&Bs[(wj + js * 16 + cc) * 40 + quad * 8];
        #pragma unroll
        for (int ms = 0; ms < 2; ++ms)
            #pragma unroll
            for (int js = 0; js < 2; ++js)
                acc[ms][js] = __builtin_amdgcn_mfma_f32_16x16x32_bf16(
                    af[ms], bfr[js], acc[ms][js], 0, 0, 0);
    }

    #pragma unroll
    for (int js = 0; js < 2; ++js) {
        int cI = c0 + wj + js * 16 + cc;
        float bi = bias[cI];
        #pragma unroll
        for (int ms = 0; ms < 2; ++ms) {
            int n = n0 + wm + ms * 16 + quad * 4;
            size_t off = ((size_t)b * 256 + cI) * NN + n;
            float4 xr = *(const float4*)&x[off];
            float4 o;
            o.x = acc[ms][js][0] + bi + xr.x;
            o.y = acc[ms][js][1] + bi + xr.y;
            o.z = acc[ms][js][2] + bi + xr.z;
            o.w = acc[ms][js][3] + bi + xr.w;
            *(float4*)&out[off] = o;
        }
    }
}

extern "C" void kernel_launch(void* const* d_in, const int* in_sizes, int n_in,
                              void* d_out, int out_size, void* d_ws, size_t ws_size,
                              hipStream_t stream)
{
    const float* x     = (const float*)d_in[0];
    const float* W_qkv = (const float*)d_in[1];
    const float* b_qkv = (const float*)d_in[2];
    const float* W_out = (const float*)d_in[3];
    const float* b_out = (const float*)d_in[4];
    float* out = (float*)d_out;

    // ws: xb 8MB | Wqt 384KB | Wot 128KB | Qb 8MB | Kb 8MB | Vtb 8MB | resb 8MB
    char* wsc = (char*)d_ws;
    unsigned short* xb   = (unsigned short*)(wsc);
    unsigned short* Wqt  = (unsigned short*)(wsc + ((size_t)8 << 20));
    unsigned short* Wot  = (unsigned short*)(wsc + ((size_t)8 << 20) + ((size_t)512 << 10));
    unsigned short* Qb   = (unsigned short*)(wsc + ((size_t)9  << 20));
    unsigned short* Kb   = (unsigned short*)(wsc + ((size_t)17 << 20));
    unsigned short* Vtb  = (unsigned short*)(wsc + ((size_t)25 << 20));
    unsigned short* resb = (unsigned short*)(wsc + ((size_t)33 << 20));

    prep_transpose<<<dim3(272, 4), 256, 0, stream>>>(x, W_qkv, W_out, xb, Wqt, Wot);
    qkv_gemm<<<dim3(6, 128), 256, 0, stream>>>(xb, Wqt, b_qkv, Qb, Kb, Vtb);
    flash_attn<<<dim3(1024), 256, 0, stream>>>(Qb, Kb, Vtb, resb);
    out_gemm<<<dim3(16, 4, 16), 256, 0, stream>>>(resb, Wot, b_out, x, out);
}

// Round 7
// 138.008 us; speedup vs baseline: 1.5117x; 1.0647x over previous
//
#include <hip/hip_runtime.h>
#include <math.h>

#define NN 1024    // 32*32 tokens per batch

typedef __attribute__((ext_vector_type(8))) __bf16 bf16x8;
typedef __attribute__((ext_vector_type(4))) __bf16 bf16x4;
typedef __attribute__((ext_vector_type(4))) float f32x4;

// Native f32->bf16 (RNE via fptrunc)
__device__ __forceinline__ unsigned short f2bf(float f) {
    __bf16 h = (__bf16)f;
    return *(unsigned short*)&h;
}
__device__ __forceinline__ ushort4 pack4(float a, float b, float c, float d) {
    bf16x4 v;
    v[0] = (__bf16)a; v[1] = (__bf16)b; v[2] = (__bf16)c; v[3] = (__bf16)d;
    return *(ushort4*)&v;
}

// Async global->LDS, 16B per lane. LDS dest must be wave-linear: base + lane*16.
__device__ __forceinline__ void async_cp16(const unsigned short* g, unsigned short* l) {
    __builtin_amdgcn_global_load_lds(
        (const __attribute__((address_space(1))) unsigned int*)g,
        (__attribute__((address_space(3))) unsigned int*)l,
        16, 0, 0);
}

// ---------------- Kernel 0: transpose + bf16 prep --------------------------
__global__ __launch_bounds__(256) void prep_transpose(
    const float* __restrict__ x, const float* __restrict__ Wq,
    const float* __restrict__ Wo,
    unsigned short* __restrict__ xb, unsigned short* __restrict__ Wqt,
    unsigned short* __restrict__ Wot)
{
    __shared__ __align__(16) unsigned short T[64 * 72];  // [r][c] bf16, pad 72
    const int bx = blockIdx.x;   // 0..271
    const int rt = blockIdx.y;   // row tile (of 256 rows) 0..3
    const float* src; unsigned short* dst; int ncol, c0;
    if (bx < 256) {
        int b = bx >> 4; int ct = bx & 15;
        src = x + (size_t)b * 256 * 1024; dst = xb + (size_t)b * 1024 * 256;
        ncol = 1024; c0 = ct * 64;
    } else if (bx < 268) {
        src = Wq; dst = Wqt; ncol = 768; c0 = (bx - 256) * 64;
    } else {
        src = Wo; dst = Wot; ncol = 256; c0 = (bx - 268) * 64;
    }
    const int t = threadIdx.x;
    #pragma unroll
    for (int i = 0; i < 4; ++i) {
        int r  = i * 16 + (t >> 4);
        int c4 = (t & 15) * 4;
        float4 v = *(const float4*)&src[(size_t)(rt * 64 + r) * ncol + c0 + c4];
        *(ushort4*)&T[r * 72 + c4] = pack4(v.x, v.y, v.z, v.w);
    }
    __syncthreads();
    #pragma unroll
    for (int i = 0; i < 2; ++i) {
        int task = t + 256 * i;          // 0..511
        int c = task & 63, rs = task >> 6;
        ushort u8[8];
        #pragma unroll
        for (int k = 0; k < 8; ++k) u8[k] = T[(rs * 8 + k) * 72 + c];
        *(uint4*)&dst[(size_t)(c0 + c) * 256 + rt * 64 + rs * 8] = *(uint4*)u8;
    }
}

// ---------------- Kernel 1: bf16 MFMA QKV GEMM (R4-proven structure) -------
// Q pre-scale now folds log2(e): S in log2 domain for exp2-based softmax.
__global__ __launch_bounds__(256, 4) void qkv_gemm(
    const unsigned short* __restrict__ xb, const unsigned short* __restrict__ Wqt,
    const float* __restrict__ bias,
    unsigned short* __restrict__ Qb, unsigned short* __restrict__ Kb,
    unsigned short* __restrict__ Vtb)
{
    __shared__ __align__(16) unsigned short As[128 * 40];  // [m][k] stride 40
    __shared__ __align__(16) unsigned short Bs[128 * 40];  // [j][k]
    const int jt = blockIdx.x;        // 0..5
    const int m0 = blockIdx.y * 128;
    const int b  = m0 >> 10;
    const int n0 = m0 & 1023;
    const int t = threadIdx.x;
    const int w = t >> 6, lane = t & 63, quad = lane >> 4, cc = lane & 15;
    const int wm = (w & 1) * 64;
    const int wj = (w >> 1) * 64;

    f32x4 acc[4][4];
    #pragma unroll
    for (int ms = 0; ms < 4; ++ms)
        #pragma unroll
        for (int js = 0; js < 4; ++js) acc[ms][js] = (f32x4)(0.f);

    for (int k0 = 0; k0 < 256; k0 += 32) {
        __syncthreads();
        #pragma unroll
        for (int i = 0; i < 2; ++i) {
            int flat = t + 256 * i;
            int row = flat >> 2, seg = flat & 3;
            *(uint4*)&As[row * 40 + seg * 8] =
                *(const uint4*)&xb[(size_t)(m0 + row) * 256 + k0 + seg * 8];
            *(uint4*)&Bs[row * 40 + seg * 8] =
                *(const uint4*)&Wqt[(size_t)(jt * 128 + row) * 256 + k0 + seg * 8];
        }
        __syncthreads();
        bf16x8 af[4], bfr[4];
        #pragma unroll
        for (int ms = 0; ms < 4; ++ms)
            af[ms] = *(bf16x8*)&As[(wm + ms * 16 + cc) * 40 + quad * 8];
        #pragma unroll
        for (int js = 0; js < 4; ++js)
            bfr[js] = *(bf16x8*)&Bs[(wj + js * 16 + cc) * 40 + quad * 8];
        #pragma unroll
        for (int ms = 0; ms < 4; ++ms)
            #pragma unroll
            for (int js = 0; js < 4; ++js)
                acc[ms][js] = __builtin_amdgcn_mfma_f32_16x16x32_bf16(
                    af[ms], bfr[js], acc[ms][js], 0, 0, 0);
    }

    const int chunk = jt * 2 + (w >> 1);
    const int h = chunk / 3, type = chunk % 3;   // 0=q 1=k 2=v
    const size_t bh = (size_t)b * 4 + h;
    float bias_r[4];
    #pragma unroll
    for (int js = 0; js < 4; ++js) bias_r[js] = bias[jt * 128 + wj + js * 16 + cc];

    if (type == 2) {
        #pragma unroll
        for (int ms = 0; ms < 4; ++ms)
            #pragma unroll
            for (int js = 0; js < 4; ++js) {
                int dd = js * 16 + cc;
                int n = n0 + wm + ms * 16 + quad * 4;
                *(ushort4*)&Vtb[(bh * 64 + dd) * NN + n] =
                    pack4(acc[ms][js][0] + bias_r[js], acc[ms][js][1] + bias_r[js],
                          acc[ms][js][2] + bias_r[js], acc[ms][js][3] + bias_r[js]);
            }
    } else {
        unsigned short* dst = type ? Kb : Qb;
        // Q: 64^-0.5 * log2(e) so S = Q·K is in log2 domain
        const float sc = type ? 1.0f : 0.18033688011112042f;
        #pragma unroll
        for (int ms = 0; ms < 4; ++ms)
            #pragma unroll
            for (int js = 0; js < 4; ++js)
                #pragma unroll
                for (int r = 0; r < 4; ++r) {
                    int n = n0 + wm + ms * 16 + quad * 4 + r;
                    dst[(bh * NN + n) * 64 + js * 16 + cc] =
                        f2bf((acc[ms][js][r] + bias_r[js]) * sc);
                }
    }
}

// ---------------- Kernel 2: flash attention, async-DMA dbuf, 40 KB LDS -----
// QP holds Q during init (fragments hoisted), then is reused as P storage.
// All tiles unpadded stride-64 with XOR chunk swizzle (sc = chunk ^ (row&7)).
__global__ __launch_bounds__(256, 4) void flash_attn(
    const unsigned short* __restrict__ Qb, const unsigned short* __restrict__ Kb,
    const unsigned short* __restrict__ Vtb, unsigned short* __restrict__ resb)
{
    __shared__ __align__(16) unsigned short QP[4096];
    __shared__ __align__(16) unsigned short Ks0[4096];
    __shared__ __align__(16) unsigned short Ks1[4096];
    __shared__ __align__(16) unsigned short Vt0[4096];
    __shared__ __align__(16) unsigned short Vt1[4096];

    const int blk = blockIdx.x;
    const int qt = blk & 15;
    const int h  = (blk >> 4) & 3;
    const int b  = blk >> 6;
    const int t  = threadIdx.x;
    const int w  = t >> 6;
    const int lane = t & 63;
    const int quad = lane >> 4;
    const int c    = lane & 15;

    const size_t bh = (size_t)(b * 4 + h);
    const unsigned short* Qg = Qb  + bh * NN * 64;
    const unsigned short* Kg = Kb  + bh * NN * 64;
    const unsigned short* Vg = Vtb + bh * 64 * NN;

    // Async-stage Q (swizzled) + K/V tile 0 into buf 0
    #pragma unroll
    for (int i = 0; i < 2; ++i) {
        int f = i * 256 + t;             // lane-linear within each wave
        int row = f >> 3;
        int gc  = (f & 7) ^ (row & 7);
        async_cp16(&Qg[(size_t)(qt * 64 + row) * 64 + gc * 8], &QP[f * 8]);
        async_cp16(&Kg[(size_t)row * 64 + gc * 8], &Ks0[f * 8]);
        async_cp16(&Vg[(size_t)row * NN + gc * 8], &Vt0[f * 8]);
    }
    __syncthreads();   // vmcnt(0) drain + barrier: tile 0 + Q ready

    // Q fragments are loop-invariant: hoist. After this, QP is P storage
    // (each wave only touches its own rows w*16+c -> no cross-wave race).
    bf16x8 qf[2];
    #pragma unroll
    for (int ks = 0; ks < 2; ++ks) {
        int sc_ = (ks * 4 + quad) ^ (c & 7);
        qf[ks] = *(bf16x8*)&QP[((w * 16 + c) * 8 + sc_) * 8];
    }

    float m_i = -INFINITY, l_i = 0.f;
    f32x4 O[4];
    #pragma unroll
    for (int dt = 0; dt < 4; ++dt) O[dt] = (f32x4)(0.f);

    auto step = [&](int kt, const unsigned short* curK, const unsigned short* curV,
                    unsigned short* nxtK, unsigned short* nxtV,
                    bool pref, bool bar) {
        if (bar) __syncthreads();
        if (pref) {
            int ktn = kt + 1;
            #pragma unroll
            for (int i = 0; i < 2; ++i) {
                int f = i * 256 + t;
                int row = f >> 3;
                int gc  = (f & 7) ^ (row & 7);
                async_cp16(&Kg[(size_t)(ktn * 64 + row) * 64 + gc * 8], &nxtK[f * 8]);
                async_cp16(&Vg[(size_t)row * NN + ktn * 64 + gc * 8], &nxtV[f * 8]);
            }
        }

        // S^T = K·Q^T (rows j, cols = this wave's q-rows); S in log2 domain
        f32x4 S[4];
        #pragma unroll
        for (int jt = 0; jt < 4; ++jt) S[jt] = (f32x4)(0.f);
        #pragma unroll
        for (int ks = 0; ks < 2; ++ks) {
            #pragma unroll
            for (int jt = 0; jt < 4; ++jt) {
                int sc_ = (ks * 4 + quad) ^ (c & 7);
                bf16x8 kf = *(bf16x8*)&curK[((jt * 16 + c) * 8 + sc_) * 8];
                S[jt] = __builtin_amdgcn_mfma_f32_16x16x32_bf16(kf, qf[ks], S[jt], 0, 0, 0);
            }
        }

        // Online softmax (log2 domain), tree-reduced
        float tj[4];
        #pragma unroll
        for (int jt = 0; jt < 4; ++jt)
            tj[jt] = fmaxf(fmaxf(S[jt][0], S[jt][1]), fmaxf(S[jt][2], S[jt][3]));
        float mt = fmaxf(fmaxf(tj[0], tj[1]), fmaxf(tj[2], tj[3]));
        mt = fmaxf(mt, __shfl_xor(mt, 16));
        mt = fmaxf(mt, __shfl_xor(mt, 32));
        float mn = fmaxf(m_i, mt);
        float alpha = __builtin_amdgcn_exp2f(m_i - mn);
        float p[4][4], rsj[4];
        #pragma unroll
        for (int jt = 0; jt < 4; ++jt) {
            #pragma unroll
            for (int r = 0; r < 4; ++r)
                p[jt][r] = __builtin_amdgcn_exp2f(S[jt][r] - mn);
            rsj[jt] = (p[jt][0] + p[jt][1]) + (p[jt][2] + p[jt][3]);
        }
        float rs = (rsj[0] + rsj[1]) + (rsj[2] + rsj[3]);
        rs += __shfl_xor(rs, 16);
        rs += __shfl_xor(rs, 32);
        l_i = l_i * alpha + rs;
        m_i = mn;

        // P -> QP (own wave's rows; swizzled b64 writes; no barrier needed)
        #pragma unroll
        for (int jt = 0; jt < 4; ++jt) {
            int scw = (jt * 2 + (quad >> 1)) ^ (c & 7);
            *(ushort4*)&QP[(w * 16 + c) * 64 + scw * 8 + (quad & 1) * 4] =
                pack4(p[jt][0], p[jt][1], p[jt][2], p[jt][3]);
        }

        float alpha_r[4];
        #pragma unroll
        for (int r = 0; r < 4; ++r) alpha_r[r] = __shfl(alpha, quad * 4 + r);
        #pragma unroll
        for (int dt = 0; dt < 4; ++dt)
            #pragma unroll
            for (int r = 0; r < 4; ++r) O[dt][r] *= alpha_r[r];

        // O += P·V
        #pragma unroll
        for (int js = 0; js < 2; ++js) {
            int scp = (js * 4 + quad) ^ (c & 7);
            bf16x8 pf = *(bf16x8*)&QP[(w * 16 + c) * 64 + scp * 8];
            #pragma unroll
            for (int dt = 0; dt < 4; ++dt) {
                int sc_ = (js * 4 + quad) ^ (c & 7);
                bf16x8 vf = *(bf16x8*)&curV[((dt * 16 + c) * 8 + sc_) * 8];
                O[dt] = __builtin_amdgcn_mfma_f32_16x16x32_bf16(pf, vf, O[dt], 0, 0, 0);
            }
        }
    };

    step(0, Ks0, Vt0, Ks1, Vt1, true, false);
    for (int kt2 = 0; kt2 < 7; ++kt2) {
        int kt = 2 * kt2 + 1;
        step(kt,     Ks1, Vt1, Ks0, Vt0, true, true);
        step(kt + 1, Ks0, Vt0, Ks1, Vt1, true, true);
    }
    step(15, Ks1, Vt1, Ks0, Vt0, false, true);

    float linv[4];
    #pragma unroll
    for (int r = 0; r < 4; ++r) linv[r] = 1.f / __shfl(l_i, quad * 4 + r);
    #pragma unroll
    for (int dt = 0; dt < 4; ++dt)
        #pragma unroll
        for (int r = 0; r < 4; ++r) {
            int row = qt * 64 + w * 16 + quad * 4 + r;
            resb[((size_t)(b * NN + row)) * 256 + h * 64 + dt * 16 + c] =
                f2bf(O[dt][r] * linv[r]);
        }
}

// ---------------- Kernel 3: bf16 MFMA out GEMM (R4-proven structure) -------
__global__ __launch_bounds__(256, 4) void out_gemm(
    const unsigned short* __restrict__ resb, const unsigned short* __restrict__ Wot,
    const float* __restrict__ bias, const float* __restrict__ x,
    float* __restrict__ out)
{
    __shared__ __align__(16) unsigned short As[64 * 40];  // res [m][k]
    __shared__ __align__(16) unsigned short Bs[64 * 40];  // Wot [j][k]
    const int n0 = blockIdx.x * 64;
    const int c0 = blockIdx.y * 64;
    const int b  = blockIdx.z;
    const int t = threadIdx.x;
    const int w = t >> 6, lane = t & 63, quad = lane >> 4, cc = lane & 15;
    const int wm = (w & 1) * 32;
    const int wj = (w >> 1) * 32;

    f32x4 acc[2][2];
    #pragma unroll
    for (int ms = 0; ms < 2; ++ms)
        #pragma unroll
        for (int js = 0; js < 2; ++js) acc[ms][js] = (f32x4)(0.f);

    for (int k0 = 0; k0 < 256; k0 += 32) {
        __syncthreads();
        {
            int r = t >> 2, seg = t & 3;   // 64 rows x 32 k per buffer
            *(uint4*)&As[r * 40 + seg * 8] =
                *(const uint4*)&resb[((size_t)b * NN + n0 + r) * 256 + k0 + seg * 8];
            *(uint4*)&Bs[r * 40 + seg * 8] =
                *(const uint4*)&Wot[(size_t)(c0 + r) * 256 + k0 + seg * 8];
        }
        __syncthreads();
        bf16x8 af[2], bfr[2];
        #pragma unroll
        for (int ms = 0; ms < 2; ++ms)
            af[ms] = *(bf16x8*)&As[(wm + ms * 16 + cc) * 40 + quad * 8];
        #pragma unroll
        for (int js = 0; js < 2; ++js)
            bfr[js] = *(bf16x8*)&Bs[(wj + js * 16 + cc) * 40 + quad * 8];
        #pragma unroll
        for (int ms = 0; ms < 2; ++ms)
            #pragma unroll
            for (int js = 0; js < 2; ++js)
                acc[ms][js] = __builtin_amdgcn_mfma_f32_16x16x32_bf16(
                    af[ms], bfr[js], acc[ms][js], 0, 0, 0);
    }

    #pragma unroll
    for (int js = 0; js < 2; ++js) {
        int cI = c0 + wj + js * 16 + cc;
        float bi = bias[cI];
        #pragma unroll
        for (int ms = 0; ms < 2; ++ms) {
            int n = n0 + wm + ms * 16 + quad * 4;
            size_t off = ((size_t)b * 256 + cI) * NN + n;
            float4 xr = *(const float4*)&x[off];
            float4 o;
            o.x = acc[ms][js][0] + bi + xr.x;
            o.y = acc[ms][js][1] + bi + xr.y;
            o.z = acc[ms][js][2] + bi + xr.z;
            o.w = acc[ms][js][3] + bi + xr.w;
            *(float4*)&out[off] = o;
        }
    }
}

extern "C" void kernel_launch(void* const* d_in, const int* in_sizes, int n_in,
                              void* d_out, int out_size, void* d_ws, size_t ws_size,
                              hipStream_t stream)
{
    const float* x     = (const float*)d_in[0];
    const float* W_qkv = (const float*)d_in[1];
    const float* b_qkv = (const float*)d_in[2];
    const float* W_out = (const float*)d_in[3];
    const float* b_out = (const float*)d_in[4];
    float* out = (float*)d_out;

    // ws: xb 8MB | Wqt 384KB | Wot 128KB | Qb 8MB | Kb 8MB | Vtb 8MB | resb 8MB
    char* wsc = (char*)d_ws;
    unsigned short* xb   = (unsigned short*)(wsc);
    unsigned short* Wqt  = (unsigned short*)(wsc + ((size_t)8 << 20));
    unsigned short* Wot  = (unsigned short*)(wsc + ((size_t)8 << 20) + ((size_t)512 << 10));
    unsigned short* Qb   = (unsigned short*)(wsc + ((size_t)9  << 20));
    unsigned short* Kb   = (unsigned short*)(wsc + ((size_t)17 << 20));
    unsigned short* Vtb  = (unsigned short*)(wsc + ((size_t)25 << 20));
    unsigned short* resb = (unsigned short*)(wsc + ((size_t)33 << 20));

    prep_transpose<<<dim3(272, 4), 256, 0, stream>>>(x, W_qkv, W_out, xb, Wqt, Wot);
    qkv_gemm<<<dim3(6, 128), 256, 0, stream>>>(xb, Wqt, b_qkv, Qb, Kb, Vtb);
    flash_attn<<<dim3(1024), 256, 0, stream>>>(Qb, Kb, Vtb, resb);
    out_gemm<<<dim3(16, 4, 16), 256, 0, stream>>>(resb, Wot, b_out, x, out);
}